// Round 7
// baseline (333.258 us; speedup 1.0000x reference)
//
#include <hip/hip_runtime.h>
#include <stdint.h>

typedef __attribute__((ext_vector_type(4)))  int   v4i;
typedef __attribute__((ext_vector_type(8)))  int   v8i;
typedef __attribute__((ext_vector_type(16))) float v16f;

#define BATCH 8192
#define KDIM  4096
#define NOUT  4096
#define KB    (KDIM / 2)     // bytes per packed fp4 row = 2048
#define BK_B  128            // K-tile bytes per row = 256 fp4 elems
#define NT    (KDIM / 256)   // 16 K-tiles

// pack x: fp32 -> fp4 e2m1 {x>0 -> 1.0 (0x2), else 0.0 (0x0)}, 8 elems/thread,
// row-major (A path unchanged, staged via LDS in the GEMM).
__global__ __launch_bounds__(256) void pack_x4(const float* __restrict__ x,
                                               uint32_t* __restrict__ xb) {
    int t = blockIdx.x * 256 + threadIdx.x;
    const float4* p = (const float4*)x + (size_t)t * 2;
    float4 f0 = p[0];
    float4 f1 = p[1];
    uint32_t b = (f0.x > 0.f ? 0x2u        : 0u)
               | (f0.y > 0.f ? 0x20u       : 0u)
               | (f0.z > 0.f ? 0x200u      : 0u)
               | (f0.w > 0.f ? 0x2000u     : 0u)
               | (f1.x > 0.f ? 0x20000u    : 0u)
               | (f1.y > 0.f ? 0x200000u   : 0u)
               | (f1.z > 0.f ? 0x2000000u  : 0u)
               | (f1.w > 0.f ? 0x20000000u : 0u);
    xb[t] = b;
}

// pack W: fp32 -> fp4 e2m1 {W>0 -> +1.0 (0x2), else -1.0 (0xA)} in
// FRAGMENT-MAJOR layout: Bf[g][T][lane] (16 B units), where
//   col = g*32 + (lane&31),  k = T*64 + (lane>>5)*32 .. +32
// so a 32x32x64-MFMA B-fragment for (col-group g, 64-k-chunk T) is one
// fully-coalesced 1-KiB wave load (lane stride 16 B). Nibbles k-ascending
// (same convention as pack_x4 / verified R1).
__global__ __launch_bounds__(256) void pack_wf(const float* __restrict__ w,
                                               uint32_t* __restrict__ wf) {
    int u = blockIdx.x * 256 + threadIdx.x;     // [0, 128*64*64)
    int lane = u & 63;
    int T    = (u >> 6) & 63;
    int g    = u >> 12;
    const float* src = w + (size_t)(g * 32 + (lane & 31)) * KDIM
                         + T * 64 + (lane >> 5) * 32;
    uint32_t wd[4];
    #pragma unroll
    for (int i = 0; i < 4; ++i) {
        float4 f0 = ((const float4*)src)[i * 2];
        float4 f1 = ((const float4*)src)[i * 2 + 1];
        wd[i] = (f0.x > 0.f ? 0x2u        : 0xAu)
              | (f0.y > 0.f ? 0x20u       : 0xA0u)
              | (f0.z > 0.f ? 0x200u      : 0xA00u)
              | (f0.w > 0.f ? 0x2000u     : 0xA000u)
              | (f1.x > 0.f ? 0x20000u    : 0xA0000u)
              | (f1.y > 0.f ? 0x200000u   : 0xA00000u)
              | (f1.z > 0.f ? 0x2000000u  : 0xA000000u)
              | (f1.w > 0.f ? 0x20000000u : 0xA0000000u);
    }
    ((uint4*)wf)[u] = make_uint4(wd[0], wd[1], wd[2], wd[3]);
}

// C[M,N] = A[M,K] * B[N,K]^T, fp4 e2m1 (values {0,1} x {-1,+1}), f32 out —
// integer-exact via unit MX scales.
// SPLIT-PIPE structure: A staged in LDS (69 TB/s pipe, double-buffered,
// global_load_lds + XOR chunk swizzle — byte-identical to verified R5 path);
// B streamed global->VGPR from the fragment-major Bf (L2-resident 8 MiB,
// one coalesced 1-KiB dwordx4 wave-load per fragment, vmcnt-tracked — no
// barrier coupling). LDS traffic per block-tile drops 256->160 KiB so the
// LDS pipe (~1.3-1.9k cyc) falls under the MFMA pipe (~2.27k cyc).
// 256x256 tile, 8 waves (2M x 4N), per-wave 128x64, BK = 256 fp4 = 128 B/row.
// MFMA: 32x32x64 f8f6f4-fp4. A row = lane&31, k-chunk = lane>>5; C/D:
// col = lane&31, row = (reg&3) + 8*(reg>>2) + 4*(lane>>5)  (verified R5/R6).
__global__ __launch_bounds__(512, 2) void bin_gemm4(const uint8_t* __restrict__ A,
                                                    const uint8_t* __restrict__ Bf,
                                                    float* __restrict__ C) {
    // A only: 2 buffers x 256 rows x 128 B = 64 KiB
    __shared__ __align__(16) uint8_t sm[65536];

    const int tid  = threadIdx.x;
    const int w    = tid >> 6;          // wave 0..7
    const int lane = tid & 63;
    const int l31  = lane & 31;         // fragment row / output col
    const int kc   = lane >> 5;         // k-chunk (16B) within 32B k-slice
    const int rsw  = lane & 7;          // (frag row) & 7, for swizzle readback

    const int Mbase = blockIdx.y * 256;
    const int Nbase = blockIdx.x * 256;
    const int wm = (w >> 2) * 128;      // wave M offset in tile
    const int wn = (w & 3) * 64;        // wave N offset in tile

    // A staging: wave w covers rows [w*32, w*32+32) in 4 groups of 8 rows.
    // One global_load_lds writes LDS base + lane*16 (1 KiB): lane -> row
    // (lane>>3), slot lane&7, fetching global chunk (lane&7)^((lane>>3)&7)
    // (group base rows are %8 == 0), i.e. LDS row r slot s = global chunk
    // s ^ (r&7). Read back chunk c of row r at slot c ^ (r&7).
    const int srow = w * 32 + (lane >> 3);
    const int swz  = ((lane & 7) ^ ((lane >> 3) & 7)) * 16;
    const uint8_t* pA = A + (size_t)(Mbase + srow) * KB + swz;

    // B fragment base: col-group gw = (Nbase+wn)/32; fragment (nb, T) at
    // pBf + (nb*64 + T)*1024, T = t*4 + ks.
    const uint8_t* pBf = Bf + (size_t)((Nbase + wn) >> 5) * 65536 + (size_t)lane * 16;

    v16f acc[4][2] = {};

    // ---- prologue: stage A tile 0 into buf 0 ----
    #pragma unroll
    for (int L = 0; L < 4; ++L)
        __builtin_amdgcn_global_load_lds(
            (__attribute__((address_space(1))) void*)(pA + (size_t)(L * 8) * KB),
            (__attribute__((address_space(3))) void*)(sm + (w * 32 + L * 8) * 128),
            16, 0, 0);
    __syncthreads();

    for (int t = 0; t < NT; ++t) {
        // ---- B fragments for tile t: 8 coalesced 1-KiB wave loads (L2) ----
        v4i bfr[2][4];
        #pragma unroll
        for (int nb = 0; nb < 2; ++nb)
            #pragma unroll
            for (int ks = 0; ks < 4; ++ks)
                bfr[nb][ks] = *(const v4i*)(pBf + (size_t)(nb * 64 + t * 4 + ks) * 1024);

        // ---- stage A tile t+1 (lands under this tile's compute) ----
        if (t + 1 < NT) {
            const int nbuf = (t + 1) & 1;
            const int kof  = (t + 1) * BK_B;
            #pragma unroll
            for (int L = 0; L < 4; ++L)
                __builtin_amdgcn_global_load_lds(
                    (__attribute__((address_space(1))) void*)(pA + (size_t)(L * 8) * KB + kof),
                    (__attribute__((address_space(3))) void*)(sm + nbuf * 32768 + (w * 32 + L * 8) * 128),
                    16, 0, 0);
        }

        // ---- compute tile t: 16 ds_read_b128 (A) + 32 MFMA ----
        const uint8_t* sA = sm + (t & 1) * 32768;
        #pragma unroll
        for (int ks = 0; ks < 4; ++ks) {
            const int slot = ((ks * 2 + kc) ^ rsw) * 16;
            v8i b8[2];
            #pragma unroll
            for (int nb = 0; nb < 2; ++nb)
                b8[nb] = (v8i){bfr[nb][ks][0], bfr[nb][ks][1],
                               bfr[nb][ks][2], bfr[nb][ks][3], 0, 0, 0, 0};
            #pragma unroll
            for (int mb = 0; mb < 4; ++mb) {
                v4i af = *(const v4i*)(sA + (wm + mb * 32 + l31) * 128 + slot);
                v8i a8 = {af[0], af[1], af[2], af[3], 0, 0, 0, 0};
                #pragma unroll
                for (int nb = 0; nb < 2; ++nb)
                    acc[mb][nb] = __builtin_amdgcn_mfma_scale_f32_32x32x64_f8f6f4(
                        a8, b8[nb], acc[mb][nb], 4, 4,
                        0, 0x7F7F7F7F, 0, 0x7F7F7F7F);
            }
        }

        // one barrier per K-tile: drains tile t+1's A-DMA (landed under
        // compute) + write-after-read protection for the buffer swap
        __syncthreads();
    }

    // C/D layout (shape-determined): col = lane&31,
    // row = (reg&3) + 8*(reg>>2) + 4*(lane>>5).
    float* Cp = C + (size_t)(Mbase + wm + 4 * kc) * NOUT + (Nbase + wn + l31);
    #pragma unroll
    for (int mb = 0; mb < 4; ++mb)
        #pragma unroll
        for (int nb = 0; nb < 2; ++nb)
            #pragma unroll
            for (int r = 0; r < 16; ++r)
                Cp[(size_t)(mb * 32 + (r & 3) + 8 * (r >> 2)) * NOUT + nb * 32]
                    = acc[mb][nb][r];
}

extern "C" void kernel_launch(void* const* d_in, const int* in_sizes, int n_in,
                              void* d_out, int out_size, void* d_ws, size_t ws_size,
                              hipStream_t stream) {
    const float* x = (const float*)d_in[0];   // [8192, 4096] f32
    const float* W = (const float*)d_in[1];   // [4096, 4096] f32, values +/-1
    float* out = (float*)d_out;               // [8192, 4096] f32

    uint8_t* xb = (uint8_t*)d_ws;                              // 16 MiB (row-major fp4)
    uint8_t* wf = (uint8_t*)d_ws + (size_t)BATCH * KDIM / 2;   // 8 MiB (fragment-major fp4)

    pack_x4<<<(BATCH * (size_t)KDIM / 8) / 256, 256, 0, stream>>>(x, (uint32_t*)xb);
    pack_wf<<<(128 * 64 * 64) / 256, 256, 0, stream>>>(W, (uint32_t*)wf);

    dim3 grid(NOUT / 256, BATCH / 256);   // (16, 32) = 512 blocks
    bin_gemm4<<<grid, 512, 0, stream>>>(xb, wf, out);
}